// Round 10
// baseline (346.902 us; speedup 1.0000x reference)
//
#include <hip/hip_runtime.h>
#include <hip/hip_bf16.h>
#include <cstdint>

#define N_TOK 32768
#define CTX   256
#define DIM   1024
#define NH    16
#define HD    64

typedef __attribute__((ext_vector_type(8))) short short8;
typedef __attribute__((ext_vector_type(4))) float f32x4;
typedef __attribute__((ext_vector_type(4))) unsigned short ushort4v;

#define AS1 __attribute__((address_space(1)))
#define AS3 __attribute__((address_space(3)))

__device__ inline unsigned short f2bf(float f) {
  union { float f; unsigned int u; } v; v.f = f;
  unsigned int r = v.u + 0x7fffu + ((v.u >> 16) & 1u);
  return (unsigned short)(r >> 16);
}

__device__ inline unsigned int cvtpk_bf16(float a, float b) {
  unsigned int r;
  asm("v_cvt_pk_bf16_f32 %0, %1, %2" : "=v"(r) : "v"(a), "v"(b));
  return r;  // low16 = bf16(a), high16 = bf16(b)
}

// ---------------- f32 -> bf16 convert (vectorized, grid-stride) ----------------
__global__ void cvt_kernel(const float* __restrict__ in, unsigned short* __restrict__ out, int n4) {
  int i = blockIdx.x * blockDim.x + threadIdx.x;
  int stride = gridDim.x * blockDim.x;
  for (int j = i; j < n4; j += stride) {
    float4 v = reinterpret_cast<const float4*>(in)[j];
    ushort4v o;
    o.x = f2bf(v.x); o.y = f2bf(v.y); o.z = f2bf(v.z); o.w = f2bf(v.w);
    reinterpret_cast<ushort4v*>(out)[j] = o;
  }
}

// batched small converts
__global__ void cvt_multi(const float* __restrict__ s0, const float* __restrict__ s1,
                          const float* __restrict__ s2, const float* __restrict__ s3,
                          const float* __restrict__ s4,
                          unsigned short* __restrict__ d0, unsigned short* __restrict__ d1,
                          unsigned short* __restrict__ d2, unsigned short* __restrict__ d3,
                          unsigned short* __restrict__ d4) {
  const float* s; unsigned short* d; int n4;
  switch (blockIdx.y) {
    case 0: s = s0; d = d0; n4 = (DIM * DIM) / 4; break;
    case 1: s = s1; d = d1; n4 = (DIM * DIM) / 4; break;
    case 2: s = s2; d = d2; n4 = (DIM * DIM) / 4; break;
    case 3: s = s3; d = d3; n4 = (DIM * DIM) / 4; break;
    default: s = s4; d = d4; n4 = (CTX * DIM) / 4; break;
  }
  int i = blockIdx.x * blockDim.x + threadIdx.x;
  int stride = gridDim.x * blockDim.x;
  for (int j = i; j < n4; j += stride) {
    float4 v = reinterpret_cast<const float4*>(s)[j];
    ushort4v o;
    o.x = f2bf(v.x); o.y = f2bf(v.y); o.z = f2bf(v.z); o.w = f2bf(v.w);
    reinterpret_cast<ushort4v*>(d)[j] = o;
  }
}

// ---------------- small bf16 GEMM (m97 structure), K/V projections ----------------
// OUTMODE: 0 = bf16 row-major; 3 = V fragment layout for attn PV:
//   Vg[h][kk*4+nf][lane][8]  (h = dcol/64, kk = c/32, nf = (d%64)/16,
//   lane = ((c%32)/8)*16 + d%16, elem = c%8)
template <int OUTMODE>
__global__ __launch_bounds__(256) void gemm_bt(const unsigned short* __restrict__ A,
                                               const unsigned short* __restrict__ B,
                                               void* __restrict__ Cout,
                                               int M, int N, int K) {
  __shared__ unsigned short As[128 * 32];
  __shared__ unsigned short Bs[128 * 32];
  const int tid  = threadIdx.x;
  const int lane = tid & 63;
  const int wid  = tid >> 6;
  const int wr = wid >> 1, wc = wid & 1;
  const int bx = blockIdx.x, by = blockIdx.y;
  const long arow0 = (long)by * 128;
  const long brow0 = (long)bx * 128;
  const int sr = tid >> 2;
  const int sc = (tid & 3) * 8;

  f32x4 acc[4][4];
#pragma unroll
  for (int i = 0; i < 4; ++i)
#pragma unroll
    for (int j = 0; j < 4; ++j) acc[i][j] = (f32x4){0.f, 0.f, 0.f, 0.f};

  const int ar = wr * 64 + (lane & 15);
  const int br = wc * 64 + (lane & 15);
  const int kc = (lane >> 4) * 8;

  for (int k0 = 0; k0 < K; k0 += 32) {
#pragma unroll
    for (int pass = 0; pass < 2; ++pass) {
      int r = pass * 64 + sr;
      const unsigned short* ga = &A[(arow0 + r) * K + k0 + sc];
      const unsigned short* gb = &B[(brow0 + r) * K + k0 + sc];
      __builtin_amdgcn_global_load_lds((const AS1 unsigned int*)ga,
                                       (AS3 unsigned int*)&As[(size_t)tid * 8 + pass * 2048], 16, 0, 0);
      __builtin_amdgcn_global_load_lds((const AS1 unsigned int*)gb,
                                       (AS3 unsigned int*)&Bs[(size_t)tid * 8 + pass * 2048], 16, 0, 0);
    }
    __syncthreads();
    short8 a[4], b[4];
#pragma unroll
    for (int mf = 0; mf < 4; ++mf) a[mf] = *(const short8*)&As[(ar + mf * 16) * 32 + kc];
#pragma unroll
    for (int nf = 0; nf < 4; ++nf) b[nf] = *(const short8*)&Bs[(br + nf * 16) * 32 + kc];
#pragma unroll
    for (int mf = 0; mf < 4; ++mf)
#pragma unroll
      for (int nf = 0; nf < 4; ++nf)
        acc[mf][nf] = __builtin_amdgcn_mfma_f32_16x16x32_bf16(a[mf], b[nf], acc[mf][nf], 0, 0, 0);
    __syncthreads();
  }

  const long row0 = (long)by * 128 + wr * 64 + ((lane >> 4) << 2);
  const long col0 = (long)bx * 128 + wc * 64 + (lane & 15);
  if (OUTMODE == 0) {
    unsigned short* C = (unsigned short*)Cout;
#pragma unroll
    for (int mf = 0; mf < 4; ++mf)
#pragma unroll
      for (int q = 0; q < 4; ++q) {
        unsigned short* cp = &C[(row0 + mf * 16 + q) * N + col0];
#pragma unroll
        for (int nf = 0; nf < 4; ++nf) cp[nf * 16] = f2bf(acc[mf][nf][q]);
      }
  } else {
    // V fragment layout (OUTMODE 3)
    unsigned short* C = (unsigned short*)Cout;
#pragma unroll
    for (int mf = 0; mf < 4; ++mf)
#pragma unroll
      for (int q = 0; q < 4; ++q) {
        const int c = (int)(row0 + mf * 16 + q);     // 0..255 (context idx)
#pragma unroll
        for (int nf = 0; nf < 4; ++nf) {
          const int dcol = (int)(col0 + nf * 16);    // 0..1023
          const size_t off = (size_t)(dcol >> 6) * 16384 +
                             (size_t)((c >> 5) * 4 + ((dcol >> 4) & 3)) * 512 +
                             (size_t)(((c >> 3) & 3) * 16 + (dcol & 15)) * 8 +
                             (size_t)(c & 7);
          C[off] = f2bf(acc[mf][nf][q]);
        }
      }
  }
}

// ---------------- big bf16 GEMM: 256x256, BK=64, 8 waves, 4-phase/2-tile schedule ----------------
// (unchanged from round 9)
template <int OUTMODE>
__global__ __launch_bounds__(512, 2) void gemm256(const unsigned short* __restrict__ A,
                                                  const unsigned short* __restrict__ B,
                                                  void* __restrict__ Cout,
                                                  int M, int N, int K, int nbx) {
  __shared__ unsigned short As[2][256 * 64];
  __shared__ unsigned short Bs[2][256 * 64];
  const int tid  = threadIdx.x;
  const int lane = tid & 63;
  const int wid  = tid >> 6;
  const int wr = wid >> 2;        // 0..1 (128-row half of C)
  const int wc = wid & 3;         // 0..3 (64-col quarter of C)
  const int lo = lane & 15, hi4 = lane >> 4, lo7 = lane & 7;

  const int nwg = gridDim.x;
  const int cpx = nwg >> 3;
  int flat = blockIdx.x;
  flat = (flat & 7) * cpx + (flat >> 3);
  const int bx = flat % nbx;
  const int by = flat / nbx;

  const long arow0 = (long)by * 256;
  const long brow0 = (long)bx * 256;
  const int nt = K >> 6;          // even
  const int nj = nt >> 1;

  auto stageA = [&](int buf, int t) {
#pragma unroll
    for (int li = 0; li < 4; ++li) {
      int gi = li * 512 + tid;
      int row = gi >> 3;
      int cg = (gi & 7) ^ (row & 7);
      __builtin_amdgcn_global_load_lds(
          (const AS1 unsigned int*)&A[(arow0 + row) * K + (t << 6) + cg * 8],
          (AS3 unsigned int*)&As[buf][gi * 8], 16, 0, 0);
    }
  };
  auto stageB = [&](int buf, int t) {
#pragma unroll
    for (int li = 0; li < 4; ++li) {
      int gi = li * 512 + tid;
      int row = gi >> 3;
      int cg = (gi & 7) ^ (row & 7);
      __builtin_amdgcn_global_load_lds(
          (const AS1 unsigned int*)&B[(brow0 + row) * K + (t << 6) + cg * 8],
          (AS3 unsigned int*)&Bs[buf][gi * 8], 16, 0, 0);
    }
  };

  f32x4 acc[8][4];
#pragma unroll
  for (int i = 0; i < 8; ++i)
#pragma unroll
    for (int j = 0; j < 4; ++j) acc[i][j] = (f32x4){0.f, 0.f, 0.f, 0.f};

  stageA(0, 0);
  stageB(0, 0);
  stageB(1, 1);

  for (int j = 0; j < nj; ++j) {
    const int p = 2 * j;
    const bool more = (j + 1 < nj);
    short8 b[4][2];

    // ---- ph1: tile p (buf0), acc rows 0-3 ----
    asm volatile("s_waitcnt vmcnt(4)" ::: "memory");
    __builtin_amdgcn_sched_barrier(0);
    __builtin_amdgcn_s_barrier();
    {
      short8 a[4][2];
#pragma unroll
      for (int nf = 0; nf < 4; ++nf)
#pragma unroll
        for (int kk = 0; kk < 2; ++kk) {
          const int row = wc * 64 + nf * 16 + lo;
          b[nf][kk] = *(const short8*)&Bs[0][row * 64 + ((kk * 4 + hi4) ^ lo7) * 8];
        }
#pragma unroll
      for (int mf = 0; mf < 4; ++mf)
#pragma unroll
        for (int kk = 0; kk < 2; ++kk) {
          const int row = wr * 128 + mf * 16 + lo;
          a[mf][kk] = *(const short8*)&As[0][row * 64 + ((kk * 4 + hi4) ^ lo7) * 8];
        }
      stageA(1, p + 1);
      __builtin_amdgcn_s_barrier();
      asm volatile("s_waitcnt lgkmcnt(0)" ::: "memory");
      __builtin_amdgcn_s_setprio(1);
#pragma unroll
      for (int kk = 0; kk < 2; ++kk)
#pragma unroll
        for (int mf = 0; mf < 4; ++mf)
#pragma unroll
          for (int nf = 0; nf < 4; ++nf)
            acc[mf][nf] = __builtin_amdgcn_mfma_f32_16x16x32_bf16(a[mf][kk], b[nf][kk], acc[mf][nf], 0, 0, 0);
      __builtin_amdgcn_s_setprio(0);
    }
    // ---- ph2: tile p (buf0), acc rows 4-7 ----
    {
      short8 a[4][2];
#pragma unroll
      for (int mf = 0; mf < 4; ++mf)
#pragma unroll
        for (int kk = 0; kk < 2; ++kk) {
          const int row = wr * 128 + (mf + 4) * 16 + lo;
          a[mf][kk] = *(const short8*)&As[0][row * 64 + ((kk * 4 + hi4) ^ lo7) * 8];
        }
      if (more) stageB(0, p + 2);
      __builtin_amdgcn_s_barrier();
      asm volatile("s_waitcnt lgkmcnt(0)" ::: "memory");
      __builtin_amdgcn_s_setprio(1);
#pragma unroll
      for (int kk = 0; kk < 2; ++kk)
#pragma unroll
        for (int mf = 0; mf < 4; ++mf)
#pragma unroll
          for (int nf = 0; nf < 4; ++nf)
            acc[mf + 4][nf] = __builtin_amdgcn_mfma_f32_16x16x32_bf16(a[mf][kk], b[nf][kk], acc[mf + 4][nf], 0, 0, 0);
      __builtin_amdgcn_s_setprio(0);
    }
    // ---- ph3: tile p+1 (buf1), acc rows 0-3 ----
    if (more) asm volatile("s_waitcnt vmcnt(4)" ::: "memory");
    else      asm volatile("s_waitcnt vmcnt(0)" ::: "memory");
    __builtin_amdgcn_sched_barrier(0);
    __builtin_amdgcn_s_barrier();
    {
      short8 a[4][2];
#pragma unroll
      for (int nf = 0; nf < 4; ++nf)
#pragma unroll
        for (int kk = 0; kk < 2; ++kk) {
          const int row = wc * 64 + nf * 16 + lo;
          b[nf][kk] = *(const short8*)&Bs[1][row * 64 + ((kk * 4 + hi4) ^ lo7) * 8];
        }
#pragma unroll
      for (int mf = 0; mf < 4; ++mf)
#pragma unroll
        for (int kk = 0; kk < 2; ++kk) {
          const int row = wr * 128 + mf * 16 + lo;
          a[mf][kk] = *(const short8*)&As[1][row * 64 + ((kk * 4 + hi4) ^ lo7) * 8];
        }
      if (more) stageA(0, p + 2);
      __builtin_amdgcn_s_barrier();
      asm volatile("s_waitcnt lgkmcnt(0)" ::: "memory");
      __builtin_amdgcn_s_setprio(1);
#pragma unroll
      for (int kk = 0; kk < 2; ++kk)
#pragma unroll
        for (int mf = 0; mf < 4; ++mf)
#pragma unroll
          for (int nf = 0; nf < 4; ++nf)
            acc[mf][nf] = __builtin_amdgcn_mfma_f32_16x16x32_bf16(a[mf][kk], b[nf][kk], acc[mf][nf], 0, 0, 0);
      __builtin_amdgcn_s_setprio(0);
    }
    // ---- ph4: tile p+1 (buf1), acc rows 4-7 ----
    {
      short8 a[4][2];
#pragma unroll
      for (int mf = 0; mf < 4; ++mf)
#pragma unroll
        for (int kk = 0; kk < 2; ++kk) {
          const int row = wr * 128 + (mf + 4) * 16 + lo;
          a[mf][kk] = *(const short8*)&As[1][row * 64 + ((kk * 4 + hi4) ^ lo7) * 8];
        }
      if (more) stageB(1, p + 3);
      __builtin_amdgcn_s_barrier();
      asm volatile("s_waitcnt lgkmcnt(0)" ::: "memory");
      __builtin_amdgcn_s_setprio(1);
#pragma unroll
      for (int kk = 0; kk < 2; ++kk)
#pragma unroll
        for (int mf = 0; mf < 4; ++mf)
#pragma unroll
          for (int nf = 0; nf < 4; ++nf)
            acc[mf + 4][nf] = __builtin_amdgcn_mfma_f32_16x16x32_bf16(a[mf][kk], b[nf][kk], acc[mf + 4][nf], 0, 0, 0);
      __builtin_amdgcn_s_setprio(0);
    }
  }

  const long row0 = (long)by * 256 + wr * 128 + (hi4 << 2);
  const long col0 = (long)bx * 256 + wc * 64 + lo;
  if (OUTMODE == 1) {
    float* C = (float*)Cout;
#pragma unroll
    for (int mf = 0; mf < 8; ++mf)
#pragma unroll
      for (int q = 0; q < 4; ++q) {
        float* cp = &C[(row0 + mf * 16 + q) * N + col0];
#pragma unroll
        for (int nf = 0; nf < 4; ++nf) cp[nf * 16] = acc[mf][nf][q];
      }
  } else {
    unsigned short* C = (unsigned short*)Cout;
#pragma unroll
    for (int mf = 0; mf < 8; ++mf)
#pragma unroll
      for (int q = 0; q < 4; ++q) {
        unsigned short* cp = &C[(row0 + mf * 16 + q) * N + col0];
#pragma unroll
        for (int nf = 0; nf < 4; ++nf) cp[nf * 16] = f2bf(acc[mf][nf][q]);
      }
  }
}

// ---------------- fused attention ----------------
// Q staged via swizzled global_load_lds (same row geometry as K); raw v_exp_f32/v_rcp_f32
// instead of OCML exp2f/div (args bounded, no denorm concerns). V direct from
// fragment-layout global. LDS 40KB -> 4 blocks/CU (4 x 40960 = 160KB exactly).
__global__ __launch_bounds__(256) void attn_kernel(const unsigned short* __restrict__ Q,
                                                   const unsigned short* __restrict__ Kc,
                                                   const unsigned short* __restrict__ Vg,
                                                   unsigned short* __restrict__ AO) {
  __shared__ unsigned short SH[256 * 64];  // K[c][d] then P[q][c] (32KB union)
  __shared__ unsigned short Qs[64 * 64];   // Q tile [q][d] (8KB), swizzled like K
  const int tid = threadIdx.x, lane = tid & 63, wid = tid >> 6;
  const int lo = lane & 15, hi4 = lane >> 4, lo7 = lane & 7;
  const int h = blockIdx.y;
  const int n0 = blockIdx.x * 64;

  // stage K_h [c=256][d=64], 16B granule (8/row) swizzled g' = g ^ (c&7)
#pragma unroll
  for (int p = 0; p < 8; ++p) {
    int gi = p * 256 + tid;
    int c  = gi >> 3;
    int gp = gi & 7;
    const unsigned short* src = &Kc[(size_t)c * DIM + h * HD + ((gp ^ (c & 7)) << 3)];
    __builtin_amdgcn_global_load_lds((const AS1 unsigned int*)src,
                                     (AS3 unsigned int*)&SH[gi * 8], 16, 0, 0);
  }
  // stage Q tile [r=64][d=64], same swizzle (coalesced 128B per row)
#pragma unroll
  for (int p = 0; p < 2; ++p) {
    int gi = p * 256 + tid;
    int r  = gi >> 3;
    int gp = gi & 7;
    const unsigned short* src = &Q[(size_t)(n0 + r) * DIM + h * HD + ((gp ^ (r & 7)) << 3)];
    __builtin_amdgcn_global_load_lds((const AS1 unsigned int*)src,
                                     (AS3 unsigned int*)&Qs[gi * 8], 16, 0, 0);
  }

  asm volatile("s_waitcnt vmcnt(0)" ::: "memory");
  __builtin_amdgcn_sched_barrier(0);
  __builtin_amdgcn_s_barrier();
  __builtin_amdgcn_sched_barrier(0);

  // Q fragments from LDS (conflict-free swizzled read, same pattern as K)
  const int g0 = hi4 ^ lo7;
  const int qr = wid * 16 + lo;
  short8 aq0 = *(const short8*)&Qs[qr * 64 + g0 * 8];
  short8 aq1 = *(const short8*)&Qs[qr * 64 + (g0 ^ 4) * 8];

  // S^T = K Q : lane holds S[q=n0+qr][c = cf*16 + hi4*4 + qi]
  f32x4 s[16];
#pragma unroll
  for (int cf = 0; cf < 16; ++cf) {
    const int r = cf * 16 + lo;
    short8 b0 = *(const short8*)&SH[r * 64 + g0 * 8];
    short8 b1 = *(const short8*)&SH[r * 64 + (g0 ^ 4) * 8];
    f32x4 z = (f32x4){0.f, 0.f, 0.f, 0.f};
    z = __builtin_amdgcn_mfma_f32_16x16x32_bf16(b0, aq0, z, 0, 0, 0);
    z = __builtin_amdgcn_mfma_f32_16x16x32_bf16(b1, aq1, z, 0, 0, 0);
    s[cf] = z;
  }

  // softmax: raw v_exp_f32 (args bounded); row-sum in-lane + 2 shfl; raw rcp
  const float cexp = 0.125f * 1.44269504088896f;  // SCALE * log2(e)
  float rs = 0.f;
#pragma unroll
  for (int cf = 0; cf < 16; ++cf)
#pragma unroll
    for (int q = 0; q < 4; ++q) {
      float p = __builtin_amdgcn_exp2f(s[cf][q] * cexp);
      s[cf][q] = p;
      rs += p;
    }
  rs += __shfl_xor(rs, 16, 64);
  rs += __shfl_xor(rs, 32, 64);
  const float rinv = __builtin_amdgcn_rcpf(rs);

  __builtin_amdgcn_s_barrier();   // all waves' K reads complete before P overwrites SH

  // prefetch first PV V-fragments (L2-hot, coalesced 1KB blocks)
  const unsigned short* vb = &Vg[(size_t)h * 16384 + (size_t)lane * 8];
  short8 bv0[4];
#pragma unroll
  for (int nf = 0; nf < 4; ++nf) bv0[nf] = *(const short8*)&vb[nf * 512];

  // P pack+write (unnormalized): row q, c0 = cf*16 + hi4*4; swizzled 16B granules
  const int pbase = (wid * 16 + lo) * 256;
  const int rx    = lo7;
#pragma unroll
  for (int cf = 0; cf < 16; ++cf) {
    unsigned int u0 = cvtpk_bf16(s[cf][0], s[cf][1]);
    unsigned int u1 = cvtpk_bf16(s[cf][2], s[cf][3]);
    const int g16 = (cf * 2 + (hi4 >> 1)) ^ rx;
    uint2 u; u.x = u0; u.y = u1;
    *(uint2*)&SH[pbase + g16 * 8 + (hi4 & 1) * 4] = u;
  }
  // P is wave-private: no barrier (wave-local RAW ordered via lgkmcnt)

  // O = P @ V : A = P[q][c-slice] from LDS; B = V fragments direct from global
  f32x4 o[4];
#pragma unroll
  for (int nf = 0; nf < 4; ++nf) o[nf] = (f32x4){0.f, 0.f, 0.f, 0.f};
#pragma unroll
  for (int kk = 0; kk < 8; ++kk) {
    const int g = (4 * kk + hi4) ^ lo7;
    short8 ap = *(const short8*)&SH[pbase + g * 8];
#pragma unroll
    for (int nf = 0; nf < 4; ++nf) {
      short8 bv = (kk == 0) ? bv0[nf] : *(const short8*)&vb[(kk * 4 + nf) * 512];
      o[nf] = __builtin_amdgcn_mfma_f32_16x16x32_bf16(ap, bv, o[nf], 0, 0, 0);
    }
  }

  // epilogue: per-row denominators via intra-wave shfl; deferred normalization
  float rq[4];
#pragma unroll
  for (int q = 0; q < 4; ++q) rq[q] = __shfl(rinv, (hi4 << 2) + q, 64);
  const size_t orow0 = n0 + wid * 16 + (hi4 << 2);
  const int ocol = h * HD + lo;
#pragma unroll
  for (int nf = 0; nf < 4; ++nf) {
    unsigned int u0 = cvtpk_bf16(o[nf][0] * rq[0], o[nf][1] * rq[1]);
    unsigned int u1 = cvtpk_bf16(o[nf][2] * rq[2], o[nf][3] * rq[3]);
    AO[(orow0 + 0) * DIM + ocol + nf * 16] = (unsigned short)u0;
    AO[(orow0 + 1) * DIM + ocol + nf * 16] = (unsigned short)(u0 >> 16);
    AO[(orow0 + 2) * DIM + ocol + nf * 16] = (unsigned short)u1;
    AO[(orow0 + 3) * DIM + ocol + nf * 16] = (unsigned short)(u1 >> 16);
  }
}

extern "C" void kernel_launch(void* const* d_in, const int* in_sizes, int n_in,
                              void* d_out, int out_size, void* d_ws, size_t ws_size,
                              hipStream_t stream) {
  (void)in_sizes; (void)n_in; (void)out_size; (void)ws_size;
  const float* x    = (const float*)d_in[0];
  const float* kv   = (const float*)d_in[1];
  // d_in[2] = rope_bias, d_in[7] = Wrope: bias constant over softmax axis -> unused.
  const float* Wq   = (const float*)d_in[3];
  const float* Wk   = (const float*)d_in[4];
  const float* Wv   = (const float*)d_in[5];
  const float* Wout = (const float*)d_in[6];
  float* out = (float*)d_out;

  char* ws = (char*)d_ws;
  unsigned short* xb  = (unsigned short*)(ws);                 // 64 MB
  unsigned short* Qb  = (unsigned short*)(ws + 67108864);      // 64 MB (reused as attn_out)
  unsigned short* wqb = (unsigned short*)(ws + 134217728);     // 2 MB each
  unsigned short* wkb = (unsigned short*)(ws + 136314880);
  unsigned short* wvb = (unsigned short*)(ws + 138412032);
  unsigned short* wob = (unsigned short*)(ws + 140509184);
  unsigned short* kvb = (unsigned short*)(ws + 142606336);     // 0.5 MB
  unsigned short* Kb  = (unsigned short*)(ws + 143130624);     // 0.5 MB
  unsigned short* Vgb = (unsigned short*)(ws + 144179200);     // 0.5 MB (V fragment layout)

  cvt_kernel<<<2048, 256, 0, stream>>>(x, xb, (N_TOK * DIM) / 4);
  cvt_multi<<<dim3(128, 5), 256, 0, stream>>>(Wq, Wk, Wv, Wout, kv,
                                              wqb, wkb, wvb, wob, kvb);

  gemm_bt<0><<<dim3(8, 2), 256, 0, stream>>>(kvb, wkb, Kb, CTX, DIM, DIM);
  gemm_bt<3><<<dim3(8, 2), 256, 0, stream>>>(kvb, wvb, Vgb, CTX, DIM, DIM);

  // Q projection: 256x256 tiles, grid = (32768/256)*(1024/256) = 512
  gemm256<0><<<512, 512, 0, stream>>>(xb, wqb, Qb, N_TOK, DIM, DIM, DIM / 256);

  attn_kernel<<<dim3(N_TOK / 64, NH), 256, 0, stream>>>(Qb, Kb, Vgb, Qb);

  // output projection (f32 out)
  gemm256<1><<<512, 512, 0, stream>>>(Qb, wob, out, N_TOK, DIM, DIM, DIM / 256);
}

// Round 11
// 305.534 us; speedup vs baseline: 1.1354x; 1.1354x over previous
//
#include <hip/hip_runtime.h>
#include <hip/hip_bf16.h>
#include <cstdint>

#define N_TOK 32768
#define CTX   256
#define DIM   1024
#define NH    16
#define HD    64

typedef __attribute__((ext_vector_type(8))) short short8;
typedef __attribute__((ext_vector_type(4))) float f32x4;
typedef __attribute__((ext_vector_type(4))) unsigned short ushort4v;

#define AS1 __attribute__((address_space(1)))
#define AS3 __attribute__((address_space(3)))

__device__ inline unsigned short f2bf(float f) {
  union { float f; unsigned int u; } v; v.f = f;
  unsigned int r = v.u + 0x7fffu + ((v.u >> 16) & 1u);
  return (unsigned short)(r >> 16);
}

__device__ inline unsigned int cvtpk_bf16(float a, float b) {
  unsigned int r;
  asm("v_cvt_pk_bf16_f32 %0, %1, %2" : "=v"(r) : "v"(a), "v"(b));
  return r;  // low16 = bf16(a), high16 = bf16(b)
}

// ---------------- f32 -> bf16 convert (vectorized, grid-stride) ----------------
__global__ void cvt_kernel(const float* __restrict__ in, unsigned short* __restrict__ out, int n4) {
  int i = blockIdx.x * blockDim.x + threadIdx.x;
  int stride = gridDim.x * blockDim.x;
  for (int j = i; j < n4; j += stride) {
    float4 v = reinterpret_cast<const float4*>(in)[j];
    ushort4v o;
    o.x = f2bf(v.x); o.y = f2bf(v.y); o.z = f2bf(v.z); o.w = f2bf(v.w);
    reinterpret_cast<ushort4v*>(out)[j] = o;
  }
}

// batched small converts
__global__ void cvt_multi(const float* __restrict__ s0, const float* __restrict__ s1,
                          const float* __restrict__ s2, const float* __restrict__ s3,
                          const float* __restrict__ s4,
                          unsigned short* __restrict__ d0, unsigned short* __restrict__ d1,
                          unsigned short* __restrict__ d2, unsigned short* __restrict__ d3,
                          unsigned short* __restrict__ d4) {
  const float* s; unsigned short* d; int n4;
  switch (blockIdx.y) {
    case 0: s = s0; d = d0; n4 = (DIM * DIM) / 4; break;
    case 1: s = s1; d = d1; n4 = (DIM * DIM) / 4; break;
    case 2: s = s2; d = d2; n4 = (DIM * DIM) / 4; break;
    case 3: s = s3; d = d3; n4 = (DIM * DIM) / 4; break;
    default: s = s4; d = d4; n4 = (CTX * DIM) / 4; break;
  }
  int i = blockIdx.x * blockDim.x + threadIdx.x;
  int stride = gridDim.x * blockDim.x;
  for (int j = i; j < n4; j += stride) {
    float4 v = reinterpret_cast<const float4*>(s)[j];
    ushort4v o;
    o.x = f2bf(v.x); o.y = f2bf(v.y); o.z = f2bf(v.z); o.w = f2bf(v.w);
    reinterpret_cast<ushort4v*>(d)[j] = o;
  }
}

// ---------------- small bf16 GEMM (m97 structure), K/V projections ----------------
// OUTMODE: 0 = bf16 row-major; 3 = V fragment layout for attn PV:
//   Vg[h][kk*4+nf][lane][8]  (h = dcol/64, kk = c/32, nf = (d%64)/16,
//   lane = ((c%32)/8)*16 + d%16, elem = c%8)
template <int OUTMODE>
__global__ __launch_bounds__(256) void gemm_bt(const unsigned short* __restrict__ A,
                                               const unsigned short* __restrict__ B,
                                               void* __restrict__ Cout,
                                               int M, int N, int K) {
  __shared__ unsigned short As[128 * 32];
  __shared__ unsigned short Bs[128 * 32];
  const int tid  = threadIdx.x;
  const int lane = tid & 63;
  const int wid  = tid >> 6;
  const int wr = wid >> 1, wc = wid & 1;
  const int bx = blockIdx.x, by = blockIdx.y;
  const long arow0 = (long)by * 128;
  const long brow0 = (long)bx * 128;
  const int sr = tid >> 2;
  const int sc = (tid & 3) * 8;

  f32x4 acc[4][4];
#pragma unroll
  for (int i = 0; i < 4; ++i)
#pragma unroll
    for (int j = 0; j < 4; ++j) acc[i][j] = (f32x4){0.f, 0.f, 0.f, 0.f};

  const int ar = wr * 64 + (lane & 15);
  const int br = wc * 64 + (lane & 15);
  const int kc = (lane >> 4) * 8;

  for (int k0 = 0; k0 < K; k0 += 32) {
#pragma unroll
    for (int pass = 0; pass < 2; ++pass) {
      int r = pass * 64 + sr;
      const unsigned short* ga = &A[(arow0 + r) * K + k0 + sc];
      const unsigned short* gb = &B[(brow0 + r) * K + k0 + sc];
      __builtin_amdgcn_global_load_lds((const AS1 unsigned int*)ga,
                                       (AS3 unsigned int*)&As[(size_t)tid * 8 + pass * 2048], 16, 0, 0);
      __builtin_amdgcn_global_load_lds((const AS1 unsigned int*)gb,
                                       (AS3 unsigned int*)&Bs[(size_t)tid * 8 + pass * 2048], 16, 0, 0);
    }
    __syncthreads();
    short8 a[4], b[4];
#pragma unroll
    for (int mf = 0; mf < 4; ++mf) a[mf] = *(const short8*)&As[(ar + mf * 16) * 32 + kc];
#pragma unroll
    for (int nf = 0; nf < 4; ++nf) b[nf] = *(const short8*)&Bs[(br + nf * 16) * 32 + kc];
#pragma unroll
    for (int mf = 0; mf < 4; ++mf)
#pragma unroll
      for (int nf = 0; nf < 4; ++nf)
        acc[mf][nf] = __builtin_amdgcn_mfma_f32_16x16x32_bf16(a[mf], b[nf], acc[mf][nf], 0, 0, 0);
    __syncthreads();
  }

  const long row0 = (long)by * 128 + wr * 64 + ((lane >> 4) << 2);
  const long col0 = (long)bx * 128 + wc * 64 + (lane & 15);
  if (OUTMODE == 0) {
    unsigned short* C = (unsigned short*)Cout;
#pragma unroll
    for (int mf = 0; mf < 4; ++mf)
#pragma unroll
      for (int q = 0; q < 4; ++q) {
        unsigned short* cp = &C[(row0 + mf * 16 + q) * N + col0];
#pragma unroll
        for (int nf = 0; nf < 4; ++nf) cp[nf * 16] = f2bf(acc[mf][nf][q]);
      }
  } else {
    // V fragment layout (OUTMODE 3)
    unsigned short* C = (unsigned short*)Cout;
#pragma unroll
    for (int mf = 0; mf < 4; ++mf)
#pragma unroll
      for (int q = 0; q < 4; ++q) {
        const int c = (int)(row0 + mf * 16 + q);     // 0..255 (context idx)
#pragma unroll
        for (int nf = 0; nf < 4; ++nf) {
          const int dcol = (int)(col0 + nf * 16);    // 0..1023
          const size_t off = (size_t)(dcol >> 6) * 16384 +
                             (size_t)((c >> 5) * 4 + ((dcol >> 4) & 3)) * 512 +
                             (size_t)(((c >> 3) & 3) * 16 + (dcol & 15)) * 8 +
                             (size_t)(c & 7);
          C[off] = f2bf(acc[mf][nf][q]);
        }
      }
  }
}

// ---------------- big bf16 GEMM: 256x256, BK=64, 8 waves, 4-phase/2-tile schedule ----------------
// (unchanged from round 9)
template <int OUTMODE>
__global__ __launch_bounds__(512, 2) void gemm256(const unsigned short* __restrict__ A,
                                                  const unsigned short* __restrict__ B,
                                                  void* __restrict__ Cout,
                                                  int M, int N, int K, int nbx) {
  __shared__ unsigned short As[2][256 * 64];
  __shared__ unsigned short Bs[2][256 * 64];
  const int tid  = threadIdx.x;
  const int lane = tid & 63;
  const int wid  = tid >> 6;
  const int wr = wid >> 2;        // 0..1 (128-row half of C)
  const int wc = wid & 3;         // 0..3 (64-col quarter of C)
  const int lo = lane & 15, hi4 = lane >> 4, lo7 = lane & 7;

  const int nwg = gridDim.x;
  const int cpx = nwg >> 3;
  int flat = blockIdx.x;
  flat = (flat & 7) * cpx + (flat >> 3);
  const int bx = flat % nbx;
  const int by = flat / nbx;

  const long arow0 = (long)by * 256;
  const long brow0 = (long)bx * 256;
  const int nt = K >> 6;          // even
  const int nj = nt >> 1;

  auto stageA = [&](int buf, int t) {
#pragma unroll
    for (int li = 0; li < 4; ++li) {
      int gi = li * 512 + tid;
      int row = gi >> 3;
      int cg = (gi & 7) ^ (row & 7);
      __builtin_amdgcn_global_load_lds(
          (const AS1 unsigned int*)&A[(arow0 + row) * K + (t << 6) + cg * 8],
          (AS3 unsigned int*)&As[buf][gi * 8], 16, 0, 0);
    }
  };
  auto stageB = [&](int buf, int t) {
#pragma unroll
    for (int li = 0; li < 4; ++li) {
      int gi = li * 512 + tid;
      int row = gi >> 3;
      int cg = (gi & 7) ^ (row & 7);
      __builtin_amdgcn_global_load_lds(
          (const AS1 unsigned int*)&B[(brow0 + row) * K + (t << 6) + cg * 8],
          (AS3 unsigned int*)&Bs[buf][gi * 8], 16, 0, 0);
    }
  };

  f32x4 acc[8][4];
#pragma unroll
  for (int i = 0; i < 8; ++i)
#pragma unroll
    for (int j = 0; j < 4; ++j) acc[i][j] = (f32x4){0.f, 0.f, 0.f, 0.f};

  stageA(0, 0);
  stageB(0, 0);
  stageB(1, 1);

  for (int j = 0; j < nj; ++j) {
    const int p = 2 * j;
    const bool more = (j + 1 < nj);
    short8 b[4][2];

    // ---- ph1: tile p (buf0), acc rows 0-3 ----
    asm volatile("s_waitcnt vmcnt(4)" ::: "memory");
    __builtin_amdgcn_sched_barrier(0);
    __builtin_amdgcn_s_barrier();
    {
      short8 a[4][2];
#pragma unroll
      for (int nf = 0; nf < 4; ++nf)
#pragma unroll
        for (int kk = 0; kk < 2; ++kk) {
          const int row = wc * 64 + nf * 16 + lo;
          b[nf][kk] = *(const short8*)&Bs[0][row * 64 + ((kk * 4 + hi4) ^ lo7) * 8];
        }
#pragma unroll
      for (int mf = 0; mf < 4; ++mf)
#pragma unroll
        for (int kk = 0; kk < 2; ++kk) {
          const int row = wr * 128 + mf * 16 + lo;
          a[mf][kk] = *(const short8*)&As[0][row * 64 + ((kk * 4 + hi4) ^ lo7) * 8];
        }
      stageA(1, p + 1);
      __builtin_amdgcn_s_barrier();
      asm volatile("s_waitcnt lgkmcnt(0)" ::: "memory");
      __builtin_amdgcn_s_setprio(1);
#pragma unroll
      for (int kk = 0; kk < 2; ++kk)
#pragma unroll
        for (int mf = 0; mf < 4; ++mf)
#pragma unroll
          for (int nf = 0; nf < 4; ++nf)
            acc[mf][nf] = __builtin_amdgcn_mfma_f32_16x16x32_bf16(a[mf][kk], b[nf][kk], acc[mf][nf], 0, 0, 0);
      __builtin_amdgcn_s_setprio(0);
    }
    // ---- ph2: tile p (buf0), acc rows 4-7 ----
    {
      short8 a[4][2];
#pragma unroll
      for (int mf = 0; mf < 4; ++mf)
#pragma unroll
        for (int kk = 0; kk < 2; ++kk) {
          const int row = wr * 128 + (mf + 4) * 16 + lo;
          a[mf][kk] = *(const short8*)&As[0][row * 64 + ((kk * 4 + hi4) ^ lo7) * 8];
        }
      if (more) stageB(0, p + 2);
      __builtin_amdgcn_s_barrier();
      asm volatile("s_waitcnt lgkmcnt(0)" ::: "memory");
      __builtin_amdgcn_s_setprio(1);
#pragma unroll
      for (int kk = 0; kk < 2; ++kk)
#pragma unroll
        for (int mf = 0; mf < 4; ++mf)
#pragma unroll
          for (int nf = 0; nf < 4; ++nf)
            acc[mf + 4][nf] = __builtin_amdgcn_mfma_f32_16x16x32_bf16(a[mf][kk], b[nf][kk], acc[mf + 4][nf], 0, 0, 0);
      __builtin_amdgcn_s_setprio(0);
    }
    // ---- ph3: tile p+1 (buf1), acc rows 0-3 ----
    if (more) asm volatile("s_waitcnt vmcnt(4)" ::: "memory");
    else      asm volatile("s_waitcnt vmcnt(0)" ::: "memory");
    __builtin_amdgcn_sched_barrier(0);
    __builtin_amdgcn_s_barrier();
    {
      short8 a[4][2];
#pragma unroll
      for (int nf = 0; nf < 4; ++nf)
#pragma unroll
        for (int kk = 0; kk < 2; ++kk) {
          const int row = wc * 64 + nf * 16 + lo;
          b[nf][kk] = *(const short8*)&Bs[1][row * 64 + ((kk * 4 + hi4) ^ lo7) * 8];
        }
#pragma unroll
      for (int mf = 0; mf < 4; ++mf)
#pragma unroll
        for (int kk = 0; kk < 2; ++kk) {
          const int row = wr * 128 + mf * 16 + lo;
          a[mf][kk] = *(const short8*)&As[1][row * 64 + ((kk * 4 + hi4) ^ lo7) * 8];
        }
      if (more) stageA(0, p + 2);
      __builtin_amdgcn_s_barrier();
      asm volatile("s_waitcnt lgkmcnt(0)" ::: "memory");
      __builtin_amdgcn_s_setprio(1);
#pragma unroll
      for (int kk = 0; kk < 2; ++kk)
#pragma unroll
        for (int mf = 0; mf < 4; ++mf)
#pragma unroll
          for (int nf = 0; nf < 4; ++nf)
            acc[mf][nf] = __builtin_amdgcn_mfma_f32_16x16x32_bf16(a[mf][kk], b[nf][kk], acc[mf][nf], 0, 0, 0);
      __builtin_amdgcn_s_setprio(0);
    }
    // ---- ph4: tile p+1 (buf1), acc rows 4-7 ----
    {
      short8 a[4][2];
#pragma unroll
      for (int mf = 0; mf < 4; ++mf)
#pragma unroll
        for (int kk = 0; kk < 2; ++kk) {
          const int row = wr * 128 + (mf + 4) * 16 + lo;
          a[mf][kk] = *(const short8*)&As[1][row * 64 + ((kk * 4 + hi4) ^ lo7) * 8];
        }
      if (more) stageB(1, p + 3);
      __builtin_amdgcn_s_barrier();
      asm volatile("s_waitcnt lgkmcnt(0)" ::: "memory");
      __builtin_amdgcn_s_setprio(1);
#pragma unroll
      for (int kk = 0; kk < 2; ++kk)
#pragma unroll
        for (int mf = 0; mf < 4; ++mf)
#pragma unroll
          for (int nf = 0; nf < 4; ++nf)
            acc[mf + 4][nf] = __builtin_amdgcn_mfma_f32_16x16x32_bf16(a[mf][kk], b[nf][kk], acc[mf + 4][nf], 0, 0, 0);
      __builtin_amdgcn_s_setprio(0);
    }
  }

  const long row0 = (long)by * 256 + wr * 128 + (hi4 << 2);
  const long col0 = (long)bx * 256 + wc * 64 + lo;
  if (OUTMODE == 1) {
    float* C = (float*)Cout;
#pragma unroll
    for (int mf = 0; mf < 8; ++mf)
#pragma unroll
      for (int q = 0; q < 4; ++q) {
        float* cp = &C[(row0 + mf * 16 + q) * N + col0];
#pragma unroll
        for (int nf = 0; nf < 4; ++nf) cp[nf * 16] = acc[mf][nf][q];
      }
  } else {
    unsigned short* C = (unsigned short*)Cout;
#pragma unroll
    for (int mf = 0; mf < 8; ++mf)
#pragma unroll
      for (int q = 0; q < 4; ++q) {
        unsigned short* cp = &C[(row0 + mf * 16 + q) * N + col0];
#pragma unroll
        for (int nf = 0; nf < 4; ++nf) cp[nf * 16] = f2bf(acc[mf][nf][q]);
      }
  }
}

// ---------------- fused attention (round-9 structure + raw exp2/rcp only) ----------------
// Q in registers (global->reg, overlapped with K staging); 32KB LDS (K/P union)
// -> 5 blocks/CU (5 x 32KB = 160KB exactly). V direct from fragment-layout global.
__global__ __launch_bounds__(256) void attn_kernel(const unsigned short* __restrict__ Q,
                                                   const unsigned short* __restrict__ Kc,
                                                   const unsigned short* __restrict__ Vg,
                                                   unsigned short* __restrict__ AO) {
  __shared__ unsigned short SH[256 * 64];  // K[c][d] then P[q][c] (32KB union)
  const int tid = threadIdx.x, lane = tid & 63, wid = tid >> 6;
  const int lo = lane & 15, hi4 = lane >> 4, lo7 = lane & 7;
  const int h = blockIdx.y;
  const int n0 = blockIdx.x * 64;

  // stage K_h [c=256][d=64], 16B granule (8/row) swizzled g' = g ^ (c&7)
#pragma unroll
  for (int p = 0; p < 8; ++p) {
    int gi = p * 256 + tid;
    int c  = gi >> 3;
    int gp = gi & 7;
    const unsigned short* src = &Kc[(size_t)c * DIM + h * HD + ((gp ^ (c & 7)) << 3)];
    __builtin_amdgcn_global_load_lds((const AS1 unsigned int*)src,
                                     (AS3 unsigned int*)&SH[gi * 8], 16, 0, 0);
  }

  // Q fragments (wave owns 16 query rows; used as MFMA B operand)
  const int qrow = n0 + wid * 16 + lo;
  const int kc = hi4 * 8;
  short8 aq0 = *(const short8*)&Q[(size_t)qrow * DIM + h * HD + kc];
  short8 aq1 = *(const short8*)&Q[(size_t)qrow * DIM + h * HD + 32 + kc];

  asm volatile("s_waitcnt vmcnt(0)" ::: "memory");
  __builtin_amdgcn_sched_barrier(0);
  __builtin_amdgcn_s_barrier();
  __builtin_amdgcn_sched_barrier(0);

  // S^T = K Q : lane holds S[q=qrow][c = cf*16 + hi4*4 + qi]
  const int g0 = hi4 ^ lo7;
  f32x4 s[16];
#pragma unroll
  for (int cf = 0; cf < 16; ++cf) {
    const int r = cf * 16 + lo;
    short8 b0 = *(const short8*)&SH[r * 64 + g0 * 8];
    short8 b1 = *(const short8*)&SH[r * 64 + (g0 ^ 4) * 8];
    f32x4 z = (f32x4){0.f, 0.f, 0.f, 0.f};
    z = __builtin_amdgcn_mfma_f32_16x16x32_bf16(b0, aq0, z, 0, 0, 0);
    z = __builtin_amdgcn_mfma_f32_16x16x32_bf16(b1, aq1, z, 0, 0, 0);
    s[cf] = z;
  }

  // softmax: raw v_exp_f32 (args bounded: |S*scale*log2e| ~< 10); raw rcp
  const float cexp = 0.125f * 1.44269504088896f;  // SCALE * log2(e)
  float rs = 0.f;
#pragma unroll
  for (int cf = 0; cf < 16; ++cf)
#pragma unroll
    for (int q = 0; q < 4; ++q) {
      float p = __builtin_amdgcn_exp2f(s[cf][q] * cexp);
      s[cf][q] = p;
      rs += p;
    }
  rs += __shfl_xor(rs, 16, 64);
  rs += __shfl_xor(rs, 32, 64);
  const float rinv = __builtin_amdgcn_rcpf(rs);

  __builtin_amdgcn_s_barrier();   // all waves' K reads complete before P overwrites SH

  // prefetch first PV V-fragments (L2-hot, coalesced 1KB blocks)
  const unsigned short* vb = &Vg[(size_t)h * 16384 + (size_t)lane * 8];
  short8 bv0[4];
#pragma unroll
  for (int nf = 0; nf < 4; ++nf) bv0[nf] = *(const short8*)&vb[nf * 512];

  // P pack+write (unnormalized): row q, c0 = cf*16 + hi4*4; swizzled 16B granules
  const int pbase = (wid * 16 + lo) * 256;
  const int rx    = lo7;
#pragma unroll
  for (int cf = 0; cf < 16; ++cf) {
    unsigned int u0 = cvtpk_bf16(s[cf][0], s[cf][1]);
    unsigned int u1 = cvtpk_bf16(s[cf][2], s[cf][3]);
    const int g16 = (cf * 2 + (hi4 >> 1)) ^ rx;
    uint2 u; u.x = u0; u.y = u1;
    *(uint2*)&SH[pbase + g16 * 8 + (hi4 & 1) * 4] = u;
  }
  // P is wave-private: no barrier (wave-local RAW ordered via lgkmcnt)

  // O = P @ V : A = P[q][c-slice] from LDS; B = V fragments direct from global
  f32x4 o[4];
#pragma unroll
  for (int nf = 0; nf < 4; ++nf) o[nf] = (f32x4){0.f, 0.f, 0.f, 0.f};
#pragma unroll
  for (int kk = 0; kk < 8; ++kk) {
    const int g = (4 * kk + hi4) ^ lo7;
    short8 ap = *(const short8*)&SH[pbase + g * 8];
#pragma unroll
    for (int nf = 0; nf < 4; ++nf) {
      short8 bv = (kk == 0) ? bv0[nf] : *(const short8*)&vb[(kk * 4 + nf) * 512];
      o[nf] = __builtin_amdgcn_mfma_f32_16x16x32_bf16(ap, bv, o[nf], 0, 0, 0);
    }
  }

  // epilogue: per-row denominators via intra-wave shfl; deferred normalization
  float rq[4];
#pragma unroll
  for (int q = 0; q < 4; ++q) rq[q] = __shfl(rinv, (hi4 << 2) + q, 64);
  const size_t orow0 = n0 + wid * 16 + (hi4 << 2);
  const int ocol = h * HD + lo;
#pragma unroll
  for (int nf = 0; nf < 4; ++nf) {
    unsigned int u0 = cvtpk_bf16(o[nf][0] * rq[0], o[nf][1] * rq[1]);
    unsigned int u1 = cvtpk_bf16(o[nf][2] * rq[2], o[nf][3] * rq[3]);
    AO[(orow0 + 0) * DIM + ocol + nf * 16] = (unsigned short)u0;
    AO[(orow0 + 1) * DIM + ocol + nf * 16] = (unsigned short)(u0 >> 16);
    AO[(orow0 + 2) * DIM + ocol + nf * 16] = (unsigned short)u1;
    AO[(orow0 + 3) * DIM + ocol + nf * 16] = (unsigned short)(u1 >> 16);
  }
}

extern "C" void kernel_launch(void* const* d_in, const int* in_sizes, int n_in,
                              void* d_out, int out_size, void* d_ws, size_t ws_size,
                              hipStream_t stream) {
  (void)in_sizes; (void)n_in; (void)out_size; (void)ws_size;
  const float* x    = (const float*)d_in[0];
  const float* kv   = (const float*)d_in[1];
  // d_in[2] = rope_bias, d_in[7] = Wrope: bias constant over softmax axis -> unused.
  const float* Wq   = (const float*)d_in[3];
  const float* Wk   = (const float*)d_in[4];
  const float* Wv   = (const float*)d_in[5];
  const float* Wout = (const float*)d_in[6];
  float* out = (float*)d_out;

  char* ws = (char*)d_ws;
  unsigned short* xb  = (unsigned short*)(ws);                 // 64 MB
  unsigned short* Qb  = (unsigned short*)(ws + 67108864);      // 64 MB (reused as attn_out)
  unsigned short* wqb = (unsigned short*)(ws + 134217728);     // 2 MB each
  unsigned short* wkb = (unsigned short*)(ws + 136314880);
  unsigned short* wvb = (unsigned short*)(ws + 138412032);
  unsigned short* wob = (unsigned short*)(ws + 140509184);
  unsigned short* kvb = (unsigned short*)(ws + 142606336);     // 0.5 MB
  unsigned short* Kb  = (unsigned short*)(ws + 143130624);     // 0.5 MB
  unsigned short* Vgb = (unsigned short*)(ws + 144179200);     // 0.5 MB (V fragment layout)

  cvt_kernel<<<2048, 256, 0, stream>>>(x, xb, (N_TOK * DIM) / 4);
  cvt_multi<<<dim3(128, 5), 256, 0, stream>>>(Wq, Wk, Wv, Wout, kv,
                                              wqb, wkb, wvb, wob, kvb);

  gemm_bt<0><<<dim3(8, 2), 256, 0, stream>>>(kvb, wkb, Kb, CTX, DIM, DIM);
  gemm_bt<3><<<dim3(8, 2), 256, 0, stream>>>(kvb, wvb, Vgb, CTX, DIM, DIM);

  // Q projection: 256x256 tiles, grid = (32768/256)*(1024/256) = 512
  gemm256<0><<<512, 512, 0, stream>>>(xb, wqb, Qb, N_TOK, DIM, DIM, DIM / 256);

  attn_kernel<<<dim3(N_TOK / 64, NH), 256, 0, stream>>>(Qb, Kb, Vgb, Qb);

  // output projection (f32 out)
  gemm256<1><<<512, 512, 0, stream>>>(Qb, wob, out, N_TOK, DIM, DIM, DIM / 256);
}